// Round 2
// baseline (456.752 us; speedup 1.0000x reference)
//
#include <hip/hip_runtime.h>
#include <math.h>

#define HEADS 6
#define SEQ   2048
#define DIM   768
#define HDIM  128
#define BATCH 4
#define MTOT  (BATCH*SEQ)   // 8192
#define NKV   (SEQ/32)      // 64

typedef float  f32x4  __attribute__((ext_vector_type(4)));
typedef __bf16 bf16x8 __attribute__((ext_vector_type(8)));
typedef __bf16 bf16x4 __attribute__((ext_vector_type(4)));
typedef float  f32x4v __attribute__((ext_vector_type(4)));

typedef __attribute__((address_space(3))) void lds_v;
typedef __attribute__((address_space(1))) void gbl_v;

__device__ __forceinline__ f32x4 mfma16(bf16x8 a, bf16x8 b, f32x4 c) {
    return __builtin_amdgcn_mfma_f32_16x16x32_bf16(a, b, c, 0, 0, 0);
}
__device__ __forceinline__ unsigned int bperm(int srclane, unsigned int v) {
    return (unsigned int)__builtin_amdgcn_ds_bpermute(srclane << 2, (int)v);
}
__device__ __forceinline__ unsigned int pack2(float lo, float hi) {
    union { __bf16 b; unsigned short u; } a, c;
    a.b = (__bf16)lo; c.b = (__bf16)hi;
    return ((unsigned int)c.u << 16) | (unsigned int)a.u;
}

// ---------------- cast x (f32 -> bf16) ----------------
__global__ __launch_bounds__(256) void cast_x_kernel(const float* __restrict__ x,
                                                     __bf16* __restrict__ xb) {
    int i = (blockIdx.x * 256 + threadIdx.x) * 4;
    f32x4v v = *(const f32x4v*)(x + i);
    bf16x4 o;
    o[0] = (__bf16)v[0]; o[1] = (__bf16)v[1];
    o[2] = (__bf16)v[2]; o[3] = (__bf16)v[3];
    *(bf16x4*)(xb + i) = o;
}

// ---------------- transpose weights W[k][n] f32 -> Wt[n][k] bf16 ----------------
__global__ __launch_bounds__(256) void transpose_w_kernel(
    const float* __restrict__ W0, const float* __restrict__ W1,
    const float* __restrict__ W2, const float* __restrict__ W3,
    __bf16* __restrict__ T0, __bf16* __restrict__ T1,
    __bf16* __restrict__ T2, __bf16* __restrict__ T3) {
    __shared__ float tile[32][33];
    const float* W; __bf16* T;
    if      (blockIdx.z == 0) { W = W0; T = T0; }
    else if (blockIdx.z == 1) { W = W1; T = T1; }
    else if (blockIdx.z == 2) { W = W2; T = T2; }
    else                      { W = W3; T = T3; }
    int n0 = blockIdx.x * 32, k0 = blockIdx.y * 32;
    int tx = threadIdx.x & 31, ty = threadIdx.x >> 5;
#pragma unroll
    for (int i = 0; i < 4; ++i)
        tile[ty + i*8][tx] = W[(size_t)(k0 + ty + i*8) * DIM + n0 + tx];
    __syncthreads();
#pragma unroll
    for (int i = 0; i < 4; ++i)
        T[(size_t)(n0 + ty + i*8) * DIM + k0 + tx] = (__bf16)tile[tx][ty + i*8];
}

// ---------------- fused QKV GEMM: [8192,768] @ Wcat[2304,768]^T ----------------
__global__ __launch_bounds__(256) void gemm_qkv(const __bf16* __restrict__ A,
                                                const __bf16* __restrict__ Wcat,
                                                const float* __restrict__ bq,
                                                const float* __restrict__ bk,
                                                const float* __restrict__ bv,
                                                __bf16* __restrict__ Qb,
                                                __bf16* __restrict__ Kb,
                                                __bf16* __restrict__ Vt) {
    constexpr int KD = DIM, NT = 2304;
    __shared__ __align__(16) __bf16 As[128 * 32];
    __shared__ __align__(16) __bf16 Bs[128 * 32];
    const int tid  = threadIdx.x;
    const int wave = tid >> 6, lane = tid & 63;
    const int l16  = lane & 15, lh = lane >> 4;
    const int bn = blockIdx.x % (NT / 128), bm = blockIdx.x / (NT / 128);
    const int m0 = bm * 128, n0 = bn * 128;
    const int wr = wave >> 1, wc = wave & 1;
    f32x4 acc[4][4] = {};

    for (int k0 = 0; k0 < KD; k0 += 32) {
#pragma unroll
        for (int ci = 0; ci < 4; ++ci) {
            int c = wave * 4 + ci;
            int t = c & 7;
            int e = (t * 64 + lane) * 8;
            int r = e >> 5, kk = e & 31;
            const __bf16* gp = (c < 8) ? (A    + (size_t)(m0 + r) * KD + k0 + kk)
                                       : (Wcat + (size_t)(n0 + r) * KD + k0 + kk);
            __bf16* lp = (c < 8 ? As : Bs) + t * 512;
            __builtin_amdgcn_global_load_lds((const gbl_v*)gp, (lds_v*)lp, 16, 0, 0);
        }
        __syncthreads();
        bf16x8 af[4], bfr[4];
#pragma unroll
        for (int i = 0; i < 4; ++i)
            af[i] = *(const bf16x8*)&As[(wr*64 + i*16 + l16) * 32 + lh*8];
#pragma unroll
        for (int j = 0; j < 4; ++j)
            bfr[j] = *(const bf16x8*)&Bs[(wc*64 + j*16 + l16) * 32 + lh*8];
#pragma unroll
        for (int i = 0; i < 4; ++i)
#pragma unroll
            for (int j = 0; j < 4; ++j)
                acc[i][j] = mfma16(af[i], bfr[j], acc[i][j]);
        __syncthreads();
    }

    const int sel = n0 / DIM;                 // 0=Q 1=K 2=V (block-uniform)
    const float* bias = sel == 0 ? bq : (sel == 1 ? bk : bv);
#pragma unroll
    for (int i = 0; i < 4; ++i) {
        int row = m0 + wr*64 + i*16 + lh*4;
#pragma unroll
        for (int j = 0; j < 4; ++j) {
            int col  = n0 + wc*64 + j*16 + l16;
            int lcol = col - sel * DIM;
            float bvv = bias[lcol];
            if (sel < 2) {
                __bf16* o = (sel == 0) ? Qb : Kb;
#pragma unroll
                for (int r = 0; r < 4; ++r)
                    o[(size_t)(row + r) * DIM + lcol] = (__bf16)(acc[i][j][r] + bvv);
            } else {
                int bb = row >> 11, ll = row & (SEQ - 1);
                int hh = lcol >> 7, dd = lcol & (HDIM - 1);
                bf16x4 pk;
#pragma unroll
                for (int r = 0; r < 4; ++r) pk[r] = (__bf16)(acc[i][j][r] + bvv);
                *(bf16x4*)&Vt[((size_t)((bb*HEADS + hh) * HDIM + dd)) * SEQ + ll] = pk;
            }
        }
    }
}

// ---------------- out-proj GEMM: [8192,768] @ Wto[768,768]^T -> f32 ----------------
__global__ __launch_bounds__(256) void gemm_out(const __bf16* __restrict__ A,
                                                const __bf16* __restrict__ Bt,
                                                const float* __restrict__ bias,
                                                float* __restrict__ outp) {
    constexpr int KD = DIM, N = DIM;
    __shared__ __align__(16) __bf16 As[128 * 32];
    __shared__ __align__(16) __bf16 Bs[128 * 32];
    const int tid  = threadIdx.x;
    const int wave = tid >> 6, lane = tid & 63;
    const int l16  = lane & 15, lh = lane >> 4;
    const int bn = blockIdx.x % (N / 128), bm = blockIdx.x / (N / 128);
    const int m0 = bm * 128, n0 = bn * 128;
    const int wr = wave >> 1, wc = wave & 1;
    f32x4 acc[4][4] = {};

    for (int k0 = 0; k0 < KD; k0 += 32) {
#pragma unroll
        for (int ci = 0; ci < 4; ++ci) {
            int c = wave * 4 + ci;
            int t = c & 7;
            int e = (t * 64 + lane) * 8;
            int r = e >> 5, kk = e & 31;
            const __bf16* gp = (c < 8) ? (A  + (size_t)(m0 + r) * KD + k0 + kk)
                                       : (Bt + (size_t)(n0 + r) * KD + k0 + kk);
            __bf16* lp = (c < 8 ? As : Bs) + t * 512;
            __builtin_amdgcn_global_load_lds((const gbl_v*)gp, (lds_v*)lp, 16, 0, 0);
        }
        __syncthreads();
        bf16x8 af[4], bfr[4];
#pragma unroll
        for (int i = 0; i < 4; ++i)
            af[i] = *(const bf16x8*)&As[(wr*64 + i*16 + l16) * 32 + lh*8];
#pragma unroll
        for (int j = 0; j < 4; ++j)
            bfr[j] = *(const bf16x8*)&Bs[(wc*64 + j*16 + l16) * 32 + lh*8];
#pragma unroll
        for (int i = 0; i < 4; ++i)
#pragma unroll
            for (int j = 0; j < 4; ++j)
                acc[i][j] = mfma16(af[i], bfr[j], acc[i][j]);
        __syncthreads();
    }

#pragma unroll
    for (int i = 0; i < 4; ++i) {
        int row = m0 + wr*64 + i*16 + lh*4;
#pragma unroll
        for (int j = 0; j < 4; ++j) {
            int col = n0 + wc*64 + j*16 + l16;
            float bv = bias[col];
#pragma unroll
            for (int r = 0; r < 4; ++r)
                outp[(size_t)(row + r) * N + col] = acc[i][j][r] + bv;
        }
    }
}

// ---------------- flash attention: 2 waves/block, 32 q-rows/wave ----------------
// Swapped QK^T: s = mfma(K,Q) -> lane holds q=l16, keys in (lh,reg).
// Softmax fully in-register; P redistributed to PV B-frag via ds_bpermute.
// PV computes O^T: o = mfma(V^T, P) -> lane holds q=l16, d in (lh,reg).
// No LDS, no barriers. Causal mask: key <= q+1 (tril k=1).
__global__ __launch_bounds__(128) void attn_kernel(const __bf16* __restrict__ Q,
                                                   const __bf16* __restrict__ K,
                                                   const __bf16* __restrict__ Vt,
                                                   __bf16* __restrict__ O) {
    const int lane = threadIdx.x & 63;
    const int wv   = threadIdx.x >> 6;             // 0..1
    const int l16  = lane & 15, lh = lane >> 4;
    const int tl   = blockIdx.x & 31;
    const int hb   = blockIdx.x >> 5;              // b*HEADS + h
    const int tile = (tl & 1) ? (31 - (tl >> 1)) : (tl >> 1);  // light/heavy interleave
    const int b = hb / HEADS, h = hb % HEADS;
    const int qw0 = tile * 64 + wv * 32;           // wave's first q row

    const float qscale = 0.08838834764831845f * 1.44269504088896f; // 1/sqrt(128)*log2e

    bf16x8 qf[2][4];
#pragma unroll
    for (int f = 0; f < 2; ++f) {
        const __bf16* qp = Q + (size_t)(b*SEQ + qw0 + f*16 + l16) * DIM + h*HDIM + lh*8;
#pragma unroll
        for (int kk = 0; kk < 4; ++kk) {
            bf16x8 v = *(const bf16x8*)(qp + kk*32);
            bf16x8 sv;
#pragma unroll
            for (int e = 0; e < 8; ++e) sv[e] = (__bf16)((float)v[e] * qscale);
            qf[f][kk] = sv;
        }
    }

    f32x4 o[2][8] = {};                            // [qfrag][dblk]
    float mx[2]   = {-INFINITY, -INFINITY};
    float lsum[2] = {0.f, 0.f};

    const int nkb = min((qw0 >> 5) + 2, NKV);
    const __bf16* kbp = K + (size_t)(b*SEQ) * DIM + h*HDIM + lh*8;
    const __bf16* vbp = Vt + (size_t)hb * HDIM * SEQ;

    for (int kb = 0; kb < nkb; ++kb) {
        const int kbase = kb * 32;
        bf16x8 kfA[4], kfB[4];
        {
            const __bf16* kp = kbp + (size_t)(kbase + l16) * DIM;
#pragma unroll
            for (int kk = 0; kk < 4; ++kk) {
                kfA[kk] = *(const bf16x8*)(kp + kk*32);
                kfB[kk] = *(const bf16x8*)(kp + 16*DIM + kk*32);
            }
        }
#pragma unroll
        for (int f = 0; f < 2; ++f) {
            const int qf0 = qw0 + f*16;
            if (kbase > qf0 + 16) continue;        // fully-masked frag (wave-uniform)
            f32x4 sA = {}, sB = {};
#pragma unroll
            for (int kk = 0; kk < 4; ++kk) {
                sA = mfma16(kfA[kk], qf[f][kk], sA);
                sB = mfma16(kfB[kk], qf[f][kk], sB);
            }
            const int q = qf0 + l16;
            float p[8];
#pragma unroll
            for (int r = 0; r < 4; ++r) { p[r] = sA[r]; p[r+4] = sB[r]; }
            if (kbase + 30 > qf0) {                // diagonal block: apply mask
#pragma unroll
                for (int r = 0; r < 4; ++r) {
                    int key = kbase + lh*4 + r;
                    if (key      > q + 1) p[r]   = -INFINITY;
                    if (key + 16 > q + 1) p[r+4] = -INFINITY;
                }
            }
            float m0 = p[0];
#pragma unroll
            for (int i = 1; i < 8; ++i) m0 = fmaxf(m0, p[i]);
            m0 = fmaxf(m0, __shfl_xor(m0, 16));
            m0 = fmaxf(m0, __shfl_xor(m0, 32));
            const float mnew = fmaxf(mx[f], m0);
            const bool grow = m0 > mx[f];
#pragma unroll
            for (int i = 0; i < 8; ++i) p[i] = exp2f(p[i] - mnew);
            float rs = 0.f;
#pragma unroll
            for (int i = 0; i < 8; ++i) rs += p[i];
            rs += __shfl_xor(rs, 16);
            rs += __shfl_xor(rs, 32);
            if (__any(grow)) {                     // exact-skip rescale
                const float resc = exp2f(mx[f] - mnew);   // ==1 on non-grow lanes
                lsum[f] = lsum[f] * resc + rs;
                mx[f] = mnew;
#pragma unroll
                for (int d = 0; d < 8; ++d)
#pragma unroll
                    for (int r = 0; r < 4; ++r) o[f][d][r] *= resc;
            } else {
                lsum[f] += rs;
            }
            // pack P to bf16 words; holder (q=l16,lh) words w0..w3 = key pairs
            // (4lh,4lh+1),(4lh+2,4lh+3),(16+4lh,..),(16+4lh+2,..)
            unsigned int w0 = pack2(p[0], p[1]);
            unsigned int w1 = pack2(p[2], p[3]);
            unsigned int w2 = pack2(p[4], p[5]);
            unsigned int w3 = pack2(p[6], p[7]);
            // requester needs keys lh*8..lh*8+7 for its q: pull from 2 lanes
            const int s0l = l16 + ((lh & 1) << 5);
            unsigned int A0 = bperm(s0l,      w0);
            unsigned int A1 = bperm(s0l,      w1);
            unsigned int A2 = bperm(s0l,      w2);
            unsigned int A3 = bperm(s0l,      w3);
            unsigned int B0 = bperm(s0l + 16, w0);
            unsigned int B1 = bperm(s0l + 16, w1);
            unsigned int B2 = bperm(s0l + 16, w2);
            unsigned int B3 = bperm(s0l + 16, w3);
            const bool hi = (lh >= 2);
            union { unsigned int u[4]; bf16x8 v; } pu;
            pu.u[0] = hi ? A2 : A0;
            pu.u[1] = hi ? A3 : A1;
            pu.u[2] = hi ? B2 : B0;
            pu.u[3] = hi ? B3 : B1;
            const bf16x8 pf = pu.v;
#pragma unroll
            for (int d = 0; d < 8; ++d) {
                bf16x8 vf = *(const bf16x8*)(vbp + (size_t)(d*16 + l16) * SEQ + kbase + lh*8);
                o[f][d] = mfma16(vf, pf, o[f][d]);
            }
        }
    }

#pragma unroll
    for (int f = 0; f < 2; ++f) {
        const float inv = 1.0f / lsum[f];
        __bf16* op = O + (size_t)(b*SEQ + qw0 + f*16 + l16) * DIM + h*HDIM;
#pragma unroll
        for (int d = 0; d < 8; ++d) {
            bf16x4 pk;
#pragma unroll
            for (int r = 0; r < 4; ++r) pk[r] = (__bf16)(o[f][d][r] * inv);
            *(bf16x4*)(op + d*16 + lh*4) = pk;
        }
    }
}

// ---------------- launch ----------------
extern "C" void kernel_launch(void* const* d_in, const int* in_sizes, int n_in,
                              void* d_out, int out_size, void* d_ws, size_t ws_size,
                              hipStream_t stream) {
    const float* x  = (const float*)d_in[0];
    const float* Wq = (const float*)d_in[1];
    const float* bq = (const float*)d_in[2];
    const float* Wk = (const float*)d_in[3];
    const float* bk = (const float*)d_in[4];
    const float* Wv = (const float*)d_in[5];
    const float* bv = (const float*)d_in[6];
    const float* Wo = (const float*)d_in[7];
    const float* bo = (const float*)d_in[8];

    char* p = (char*)d_ws;
    const size_t SZ_X = (size_t)MTOT * DIM * 2;        // 12.6 MB
    const size_t SZ_W = (size_t)DIM * DIM * 2;         // 1.18 MB
    __bf16* xb   = (__bf16*)p; p += SZ_X;
    __bf16* Wcat = (__bf16*)p; p += 3 * SZ_W;          // [2304][768]
    __bf16* Wto  = (__bf16*)p; p += SZ_W;
    __bf16* Qb   = (__bf16*)p; p += SZ_X;
    __bf16* Kb   = (__bf16*)p; p += SZ_X;
    __bf16* Vt   = (__bf16*)p; p += SZ_X;
    __bf16* Ob   = (__bf16*)p; p += SZ_X;

    cast_x_kernel<<<(MTOT * DIM) / 1024, 256, 0, stream>>>(x, xb);
    transpose_w_kernel<<<dim3(DIM/32, DIM/32, 4), 256, 0, stream>>>(
        Wq, Wk, Wv, Wo,
        Wcat, Wcat + (size_t)DIM*DIM, Wcat + (size_t)2*DIM*DIM, Wto);

    gemm_qkv<<<(MTOT/128) * (2304/128), 256, 0, stream>>>(xb, Wcat, bq, bk, bv, Qb, Kb, Vt);

    attn_kernel<<<BATCH * HEADS * (SEQ / 64), 128, 0, stream>>>(Qb, Kb, Vt, Ob);

    gemm_out<<<(MTOT/128) * (DIM/128), 256, 0, stream>>>(Ob, Wto, bo, (float*)d_out);
}

// Round 3
// 184.952 us; speedup vs baseline: 2.4696x; 2.4696x over previous
//
#include <hip/hip_runtime.h>
#include <math.h>

#define HEADS 6
#define SEQ   2048
#define DIM   768
#define HDIM  128
#define BATCH 4
#define MTOT  (BATCH*SEQ)   // 8192
#define NKV   (SEQ/32)      // 64

typedef float  f32x4  __attribute__((ext_vector_type(4)));
typedef __bf16 bf16x8 __attribute__((ext_vector_type(8)));
typedef __bf16 bf16x4 __attribute__((ext_vector_type(4)));
typedef float  f32x4v __attribute__((ext_vector_type(4)));

typedef __attribute__((address_space(3))) void lds_v;
typedef __attribute__((address_space(1))) void gbl_v;

__device__ __forceinline__ f32x4 mfma16(bf16x8 a, bf16x8 b, f32x4 c) {
    return __builtin_amdgcn_mfma_f32_16x16x32_bf16(a, b, c, 0, 0, 0);
}
__device__ __forceinline__ unsigned int bperm(int srclane, unsigned int v) {
    return (unsigned int)__builtin_amdgcn_ds_bpermute(srclane << 2, (int)v);
}
__device__ __forceinline__ unsigned int pack2(float lo, float hi) {
    union { __bf16 b; unsigned short u; } a, c;
    a.b = (__bf16)lo; c.b = (__bf16)hi;
    return ((unsigned int)c.u << 16) | (unsigned int)a.u;
}

// ---------------- cast x (f32 -> bf16) ----------------
__global__ __launch_bounds__(256) void cast_x_kernel(const float* __restrict__ x,
                                                     __bf16* __restrict__ xb) {
    int i = (blockIdx.x * 256 + threadIdx.x) * 4;
    f32x4v v = *(const f32x4v*)(x + i);
    bf16x4 o;
    o[0] = (__bf16)v[0]; o[1] = (__bf16)v[1];
    o[2] = (__bf16)v[2]; o[3] = (__bf16)v[3];
    *(bf16x4*)(xb + i) = o;
}

// ---------------- transpose weights W[k][n] f32 -> Wt[n][k] bf16 ----------------
__global__ __launch_bounds__(256) void transpose_w_kernel(
    const float* __restrict__ W0, const float* __restrict__ W1,
    const float* __restrict__ W2, const float* __restrict__ W3,
    __bf16* __restrict__ T0, __bf16* __restrict__ T1,
    __bf16* __restrict__ T2, __bf16* __restrict__ T3) {
    __shared__ float tile[32][33];
    const float* W; __bf16* T;
    if      (blockIdx.z == 0) { W = W0; T = T0; }
    else if (blockIdx.z == 1) { W = W1; T = T1; }
    else if (blockIdx.z == 2) { W = W2; T = T2; }
    else                      { W = W3; T = T3; }
    int n0 = blockIdx.x * 32, k0 = blockIdx.y * 32;
    int tx = threadIdx.x & 31, ty = threadIdx.x >> 5;
#pragma unroll
    for (int i = 0; i < 4; ++i)
        tile[ty + i*8][tx] = W[(size_t)(k0 + ty + i*8) * DIM + n0 + tx];
    __syncthreads();
#pragma unroll
    for (int i = 0; i < 4; ++i)
        T[(size_t)(n0 + ty + i*8) * DIM + k0 + tx] = (__bf16)tile[tx][ty + i*8];
}

// ---------------- fused QKV GEMM: [8192,768] @ Wcat[2304,768]^T ----------------
__global__ __launch_bounds__(256) void gemm_qkv(const __bf16* __restrict__ A,
                                                const __bf16* __restrict__ Wcat,
                                                const float* __restrict__ bq,
                                                const float* __restrict__ bk,
                                                const float* __restrict__ bv,
                                                __bf16* __restrict__ Qb,
                                                __bf16* __restrict__ Kb,
                                                __bf16* __restrict__ Vt) {
    constexpr int KD = DIM, NT = 2304;
    __shared__ __align__(16) __bf16 As[128 * 32];
    __shared__ __align__(16) __bf16 Bs[128 * 32];
    const int tid  = threadIdx.x;
    const int wave = tid >> 6, lane = tid & 63;
    const int l16  = lane & 15, lh = lane >> 4;
    const int bn = blockIdx.x % (NT / 128), bm = blockIdx.x / (NT / 128);
    const int m0 = bm * 128, n0 = bn * 128;
    const int wr = wave >> 1, wc = wave & 1;
    f32x4 acc[4][4] = {};

    for (int k0 = 0; k0 < KD; k0 += 32) {
#pragma unroll
        for (int ci = 0; ci < 4; ++ci) {
            int c = wave * 4 + ci;
            int t = c & 7;
            int e = (t * 64 + lane) * 8;
            int r = e >> 5, kk = e & 31;
            const __bf16* gp = (c < 8) ? (A    + (size_t)(m0 + r) * KD + k0 + kk)
                                       : (Wcat + (size_t)(n0 + r) * KD + k0 + kk);
            __bf16* lp = (c < 8 ? As : Bs) + t * 512;
            __builtin_amdgcn_global_load_lds((const gbl_v*)gp, (lds_v*)lp, 16, 0, 0);
        }
        __syncthreads();
        bf16x8 af[4], bfr[4];
#pragma unroll
        for (int i = 0; i < 4; ++i)
            af[i] = *(const bf16x8*)&As[(wr*64 + i*16 + l16) * 32 + lh*8];
#pragma unroll
        for (int j = 0; j < 4; ++j)
            bfr[j] = *(const bf16x8*)&Bs[(wc*64 + j*16 + l16) * 32 + lh*8];
#pragma unroll
        for (int i = 0; i < 4; ++i)
#pragma unroll
            for (int j = 0; j < 4; ++j)
                acc[i][j] = mfma16(af[i], bfr[j], acc[i][j]);
        __syncthreads();
    }

    const int sel = n0 / DIM;                 // 0=Q 1=K 2=V (block-uniform)
    const float* bias = sel == 0 ? bq : (sel == 1 ? bk : bv);
#pragma unroll
    for (int i = 0; i < 4; ++i) {
        int row = m0 + wr*64 + i*16 + lh*4;
#pragma unroll
        for (int j = 0; j < 4; ++j) {
            int col  = n0 + wc*64 + j*16 + l16;
            int lcol = col - sel * DIM;
            float bvv = bias[lcol];
            if (sel < 2) {
                __bf16* o = (sel == 0) ? Qb : Kb;
#pragma unroll
                for (int r = 0; r < 4; ++r)
                    o[(size_t)(row + r) * DIM + lcol] = (__bf16)(acc[i][j][r] + bvv);
            } else {
                int bb = row >> 11, ll = row & (SEQ - 1);
                int hh = lcol >> 7, dd = lcol & (HDIM - 1);
                bf16x4 pk;
#pragma unroll
                for (int r = 0; r < 4; ++r) pk[r] = (__bf16)(acc[i][j][r] + bvv);
                *(bf16x4*)&Vt[((size_t)((bb*HEADS + hh) * HDIM + dd)) * SEQ + ll] = pk;
            }
        }
    }
}

// ---------------- out-proj GEMM: [8192,768] @ Wto[768,768]^T -> f32 ----------------
__global__ __launch_bounds__(256) void gemm_out(const __bf16* __restrict__ A,
                                                const __bf16* __restrict__ Bt,
                                                const float* __restrict__ bias,
                                                float* __restrict__ outp) {
    constexpr int KD = DIM, N = DIM;
    __shared__ __align__(16) __bf16 As[128 * 32];
    __shared__ __align__(16) __bf16 Bs[128 * 32];
    const int tid  = threadIdx.x;
    const int wave = tid >> 6, lane = tid & 63;
    const int l16  = lane & 15, lh = lane >> 4;
    const int bn = blockIdx.x % (N / 128), bm = blockIdx.x / (N / 128);
    const int m0 = bm * 128, n0 = bn * 128;
    const int wr = wave >> 1, wc = wave & 1;
    f32x4 acc[4][4] = {};

    for (int k0 = 0; k0 < KD; k0 += 32) {
#pragma unroll
        for (int ci = 0; ci < 4; ++ci) {
            int c = wave * 4 + ci;
            int t = c & 7;
            int e = (t * 64 + lane) * 8;
            int r = e >> 5, kk = e & 31;
            const __bf16* gp = (c < 8) ? (A  + (size_t)(m0 + r) * KD + k0 + kk)
                                       : (Bt + (size_t)(n0 + r) * KD + k0 + kk);
            __bf16* lp = (c < 8 ? As : Bs) + t * 512;
            __builtin_amdgcn_global_load_lds((const gbl_v*)gp, (lds_v*)lp, 16, 0, 0);
        }
        __syncthreads();
        bf16x8 af[4], bfr[4];
#pragma unroll
        for (int i = 0; i < 4; ++i)
            af[i] = *(const bf16x8*)&As[(wr*64 + i*16 + l16) * 32 + lh*8];
#pragma unroll
        for (int j = 0; j < 4; ++j)
            bfr[j] = *(const bf16x8*)&Bs[(wc*64 + j*16 + l16) * 32 + lh*8];
#pragma unroll
        for (int i = 0; i < 4; ++i)
#pragma unroll
            for (int j = 0; j < 4; ++j)
                acc[i][j] = mfma16(af[i], bfr[j], acc[i][j]);
        __syncthreads();
    }

#pragma unroll
    for (int i = 0; i < 4; ++i) {
        int row = m0 + wr*64 + i*16 + lh*4;
#pragma unroll
        for (int j = 0; j < 4; ++j) {
            int col = n0 + wc*64 + j*16 + l16;
            float bv = bias[col];
#pragma unroll
            for (int r = 0; r < 4; ++r)
                outp[(size_t)(row + r) * N + col] = acc[i][j][r] + bv;
        }
    }
}

// ---------------- flash attention, split-K, LDS-staged K/V ----------------
// Block = 4 waves x 16 q-rows = 64 q-rows. Chunk c handles k-blocks kb ≡ c (mod ks).
// K/V double-buffered in LDS via global_load_lds with XOR-swizzled source.
// Swapped QK^T (s = mfma(K,Q)); softmax in-register; P via ds_bpermute;
// PV computes O^T (o = mfma(V^T, P)). Causal mask: key <= q+1 (tril k=1).
// ks==1: write Ob directly. ks==2: write partials (po bf16, pm/pl f32).
__global__ __launch_bounds__(256, 3) void attn_kernel(
    const __bf16* __restrict__ Q, const __bf16* __restrict__ K,
    const __bf16* __restrict__ Vt,
    __bf16* __restrict__ po, float* __restrict__ pm, float* __restrict__ pl,
    __bf16* __restrict__ Ob, int ks) {
    __shared__ __align__(16) __bf16 Ks[2][32 * 128];
    __shared__ __align__(16) __bf16 Vs[2][128 * 32];
    const int lane = threadIdx.x & 63, wv = threadIdx.x >> 6;
    const int l16 = lane & 15, lh = lane >> 4;
    // grid: 8 xcd x 3 bh_l x 32 tl x ks  -> bh pinned to XCD (blockIdx % 8)
    const int id  = blockIdx.x;
    const int xcd = id & 7;
    const int idx = id >> 3;
    const int bh_l = idx % 3, rem = idx / 3;
    const int c = rem % ks, tl = rem / ks;
    const int tile = (tl & 1) ? (31 - (tl >> 1)) : (tl >> 1);   // heavy/light mix
    const int bh = xcd + 8 * bh_l;
    const int b = bh / HEADS, h = bh - b * HEADS;
    const int qw0 = tile * 64 + wv * 16;
    const float qs = 0.12751674770951932f;  // 1/sqrt(128) * log2(e)

    bf16x8 qf[4];
    {
        const __bf16* qp = Q + (size_t)(b*SEQ + qw0 + l16) * DIM + h*HDIM + lh*8;
#pragma unroll
        for (int kk = 0; kk < 4; ++kk) {
            bf16x8 v = *(const bf16x8*)(qp + kk*32);
            bf16x8 sv;
#pragma unroll
            for (int e = 0; e < 8; ++e) sv[e] = (__bf16)((float)v[e] * qs);
            qf[kk] = sv;
        }
    }

    const __bf16* kgb = K  + (size_t)(b*SEQ) * DIM + h*HDIM;
    const __bf16* vgb = Vt + (size_t)bh * HDIM * SEQ;

    // stage one k-block (K: 32x128 swizzled, V: 128x32 swizzled) -> 16 lds-loads/4 waves
    auto stage = [&](int buf, int kb) {
        const int kbase = kb * 32;
#pragma unroll
        for (int s = 0; s < 4; ++s) {
            const int j = wv * 4 + s;          // wave-uniform
            if (j < 8) {
                const int row = j * 4 + (lane >> 4);
                const int c16 = (lane & 15) ^ (row & 7);      // pre-swizzled source
                const __bf16* gp = kgb + (size_t)(kbase + row) * DIM + c16 * 8;
                __builtin_amdgcn_global_load_lds((const gbl_v*)gp,
                    (lds_v*)&Ks[buf][j * 512], 16, 0, 0);
            } else {
                const int jj = j - 8;
                const int row = jj * 16 + (lane >> 2);
                const int c16 = (lane & 3) ^ ((row >> 1) & 3);
                const __bf16* gp = vgb + (size_t)row * SEQ + kbase + c16 * 8;
                __builtin_amdgcn_global_load_lds((const gbl_v*)gp,
                    (lds_v*)&Vs[buf][jj * 512], 16, 0, 0);
            }
        }
    };

    f32x4 o[8] = {};
    float mx = -INFINITY, lsum = 0.f;
    const int nkb = min(2 * tile + 3, NKV);
    const int cnt = (nkb - c + ks - 1) / ks;

    stage(0, c);
    asm volatile("s_waitcnt vmcnt(0)" ::: "memory");
    __builtin_amdgcn_s_barrier();

    int cur = 0;
    for (int i = 0; i < cnt; ++i) {
        const int kb = c + i * ks;
        const int kbase = kb * 32;
        const bool more = (i + 1 < cnt);       // block-uniform
        if (more) {
            stage(cur ^ 1, kb + ks);
            asm volatile("s_waitcnt vmcnt(4)" ::: "memory");  // prev stage done, next in flight
        } else {
            asm volatile("s_waitcnt vmcnt(0)" ::: "memory");
        }
        __builtin_amdgcn_s_barrier();          // buf[cur] valid for all waves

        if (kbase <= qw0 + 16) {               // wave-uniform activity test
            bf16x8 kfA[4], kfB[4];
#pragma unroll
            for (int kk = 0; kk < 4; ++kk) {
                const int ca = (kk*4 + lh) ^ (l16 & 7);
                kfA[kk] = *(const bf16x8*)&Ks[cur][l16 * 128 + ca * 8];
                const int rb = 16 + l16;
                const int cb = (kk*4 + lh) ^ (rb & 7);
                kfB[kk] = *(const bf16x8*)&Ks[cur][rb * 128 + cb * 8];
            }
            f32x4 sA = {}, sB = {};
            __builtin_amdgcn_s_setprio(1);
#pragma unroll
            for (int kk = 0; kk < 4; ++kk) {
                sA = mfma16(kfA[kk], qf[kk], sA);
                sB = mfma16(kfB[kk], qf[kk], sB);
            }
            __builtin_amdgcn_s_setprio(0);
            const int q = qw0 + l16;
            float p[8];
#pragma unroll
            for (int r = 0; r < 4; ++r) { p[r] = sA[r]; p[r+4] = sB[r]; }
            if (kbase + 30 > qw0) {            // diagonal: apply causal mask
#pragma unroll
                for (int r = 0; r < 4; ++r) {
                    const int key = kbase + lh*4 + r;
                    if (key      > q + 1) p[r]   = -INFINITY;
                    if (key + 16 > q + 1) p[r+4] = -INFINITY;
                }
            }
            float m0 = p[0];
#pragma unroll
            for (int t2 = 1; t2 < 8; ++t2) m0 = fmaxf(m0, p[t2]);
            m0 = fmaxf(m0, __shfl_xor(m0, 16));
            m0 = fmaxf(m0, __shfl_xor(m0, 32));
            const float mnew = fmaxf(mx, m0);
            const bool grow = m0 > mx;
            const float mref = (mnew == -INFINITY) ? 0.f : mnew;  // NaN guard (split-K)
#pragma unroll
            for (int t2 = 0; t2 < 8; ++t2) p[t2] = exp2f(p[t2] - mref);
            float rs = 0.f;
#pragma unroll
            for (int t2 = 0; t2 < 8; ++t2) rs += p[t2];
            rs += __shfl_xor(rs, 16);
            rs += __shfl_xor(rs, 32);
            if (__any(grow)) {
                const float resc = (mx < mnew) ? exp2f(mx - mnew) : 1.0f;  // NaN guard
                lsum = lsum * resc + rs;
                mx = mnew;
#pragma unroll
                for (int d = 0; d < 8; ++d)
#pragma unroll
                    for (int r = 0; r < 4; ++r) o[d][r] *= resc;
            } else {
                lsum += rs;
            }
            unsigned int w0 = pack2(p[0], p[1]);
            unsigned int w1 = pack2(p[2], p[3]);
            unsigned int w2 = pack2(p[4], p[5]);
            unsigned int w3 = pack2(p[6], p[7]);
            const int s0l = l16 + ((lh & 1) << 5);
            unsigned int A0 = bperm(s0l,      w0), A1 = bperm(s0l,      w1);
            unsigned int A2 = bperm(s0l,      w2), A3 = bperm(s0l,      w3);
            unsigned int B0 = bperm(s0l + 16, w0), B1 = bperm(s0l + 16, w1);
            unsigned int B2 = bperm(s0l + 16, w2), B3 = bperm(s0l + 16, w3);
            const bool hi = (lh >= 2);
            union { unsigned int u[4]; bf16x8 v; } pu;
            pu.u[0] = hi ? A2 : A0;
            pu.u[1] = hi ? A3 : A1;
            pu.u[2] = hi ? B2 : B0;
            pu.u[3] = hi ? B3 : B1;
            const bf16x8 pf = pu.v;
            __builtin_amdgcn_s_setprio(1);
#pragma unroll
            for (int d = 0; d < 8; ++d) {
                const int row = d * 16 + l16;
                const int cv = lh ^ ((row >> 1) & 3);
                bf16x8 vf = *(const bf16x8*)&Vs[cur][row * 32 + cv * 8];
                o[d] = mfma16(vf, pf, o[d]);
            }
            __builtin_amdgcn_s_setprio(0);
        }
        __builtin_amdgcn_s_barrier();          // buf[cur] reads done before overwrite
        cur ^= 1;
    }

    if (ks == 1) {
        const float inv = 1.0f / lsum;
        __bf16* op = Ob + (size_t)(b*SEQ + qw0 + l16) * DIM + h*HDIM;
#pragma unroll
        for (int d = 0; d < 8; ++d) {
            bf16x4 pk;
#pragma unroll
            for (int r = 0; r < 4; ++r) pk[r] = (__bf16)(o[d][r] * inv);
            *(bf16x4*)(op + d*16 + lh*4) = pk;
        }
    } else {
        const int pid = (bh * 32 + tile) * ks + c;
        const int lq  = wv * 16 + l16;
        __bf16* pop = po + ((size_t)pid * 64 + lq) * HDIM;
#pragma unroll
        for (int d = 0; d < 8; ++d) {
            bf16x4 pk;
#pragma unroll
            for (int r = 0; r < 4; ++r) pk[r] = (__bf16)o[d][r];
            *(bf16x4*)(pop + d*16 + lh*4) = pk;
        }
        if (lh == 0) {
            pm[(size_t)pid * 64 + lq] = mx;
            pl[(size_t)pid * 64 + lq] = lsum;
        }
    }
}

// ---------------- merge split-K partials ----------------
__global__ __launch_bounds__(256) void merge_kernel(const __bf16* __restrict__ po,
    const float* __restrict__ pm, const float* __restrict__ pl,
    __bf16* __restrict__ Ob, int ks) {
    const int id = blockIdx.x;             // bh*32 + tile
    const int bh = id >> 5, tile = id & 31;
    const int b = bh / HEADS, h = bh - b * HEADS;
    const int lq = threadIdx.x >> 2;
    const int d0 = (threadIdx.x & 3) * 32;
    const int pb = id * ks;
    float M = -INFINITY;
    for (int cc = 0; cc < ks; ++cc) M = fmaxf(M, pm[(size_t)(pb + cc) * 64 + lq]);
    float L = 0.f, w[2] = {0.f, 0.f};
    for (int cc = 0; cc < ks; ++cc) {
        w[cc] = exp2f(pm[(size_t)(pb + cc) * 64 + lq] - M);
        L += w[cc] * pl[(size_t)(pb + cc) * 64 + lq];
    }
    const float invL = 1.0f / L;
    __bf16* op = Ob + (size_t)(b*SEQ + tile*64 + lq) * DIM + h*HDIM;
#pragma unroll
    for (int d = 0; d < 32; d += 8) {
        float acc[8] = {};
        for (int cc = 0; cc < ks; ++cc) {
            bf16x8 v = *(const bf16x8*)&po[((size_t)(pb + cc) * 64 + lq) * HDIM + d0 + d];
            const float wc = w[cc];
#pragma unroll
            for (int e = 0; e < 8; ++e) acc[e] += wc * (float)v[e];
        }
        bf16x8 ov;
#pragma unroll
        for (int e = 0; e < 8; ++e) ov[e] = (__bf16)(acc[e] * invL);
        *(bf16x8*)(op + d0 + d) = ov;
    }
}

// ---------------- launch ----------------
extern "C" void kernel_launch(void* const* d_in, const int* in_sizes, int n_in,
                              void* d_out, int out_size, void* d_ws, size_t ws_size,
                              hipStream_t stream) {
    const float* x  = (const float*)d_in[0];
    const float* Wq = (const float*)d_in[1];
    const float* bq = (const float*)d_in[2];
    const float* Wk = (const float*)d_in[3];
    const float* bk = (const float*)d_in[4];
    const float* Wv = (const float*)d_in[5];
    const float* bv = (const float*)d_in[6];
    const float* Wo = (const float*)d_in[7];
    const float* bo = (const float*)d_in[8];

    char* p = (char*)d_ws;
    const size_t SZ_X = (size_t)MTOT * DIM * 2;        // 12.6 MB
    const size_t SZ_W = (size_t)DIM * DIM * 2;         // 1.18 MB
    __bf16* xb   = (__bf16*)p; p += SZ_X;
    __bf16* Wcat = (__bf16*)p; p += 3 * SZ_W;          // [2304][768]
    __bf16* Wto  = (__bf16*)p; p += SZ_W;
    __bf16* Qb   = (__bf16*)p; p += SZ_X;
    __bf16* Kb   = (__bf16*)p; p += SZ_X;
    __bf16* Vt   = (__bf16*)p; p += SZ_X;
    __bf16* Ob   = (__bf16*)p; p += SZ_X;

    const size_t base = (size_t)(p - (char*)d_ws);
    const size_t SZ_PO = (size_t)24 * 32 * 2 * 64 * HDIM * 2;  // 25.2 MB (ks=2)
    const size_t SZ_PM = (size_t)24 * 32 * 2 * 64 * 4;         // 0.39 MB
    const int ks = (ws_size >= base + SZ_PO + 2 * SZ_PM) ? 2 : 1;
    __bf16* po = (__bf16*)p;            p += SZ_PO;
    float*  pmv = (float*)p;            p += SZ_PM;
    float*  plv = (float*)p;

    cast_x_kernel<<<(MTOT * DIM) / 1024, 256, 0, stream>>>(x, xb);
    transpose_w_kernel<<<dim3(DIM/32, DIM/32, 4), 256, 0, stream>>>(
        Wq, Wk, Wv, Wo,
        Wcat, Wcat + (size_t)DIM*DIM, Wcat + (size_t)2*DIM*DIM, Wto);

    gemm_qkv<<<(MTOT/128) * (2304/128), 256, 0, stream>>>(xb, Wcat, bq, bk, bv, Qb, Kb, Vt);

    attn_kernel<<<768 * ks, 256, 0, stream>>>(Qb, Kb, Vt, po, pmv, plv, Ob, ks);
    if (ks == 2)
        merge_kernel<<<24 * 32, 256, 0, stream>>>(po, pmv, plv, Ob, ks);

    gemm_out<<<(MTOT/128) * (DIM/128), 256, 0, stream>>>(Ob, Wto, bo, (float*)d_out);
}